// Round 2
// baseline (569.536 us; speedup 1.0000x reference)
//
#include <hip/hip_runtime.h>
#include <math.h>

typedef unsigned short u16;
typedef unsigned int u32;
typedef __attribute__((ext_vector_type(4))) float f4;
typedef __attribute__((ext_vector_type(4))) u16 u16x4;
typedef __attribute__((ext_vector_type(8))) u16 u16x8;
typedef __attribute__((ext_vector_type(8))) short bf8;

#define N_IMG 8
#define HS 128               // half spatial
#define NPOS (N_IMG*HS*HS)   // 131072
#define IN_CH 192
#define HID_CH 384

__device__ __forceinline__ u16 f2bf(float f) {
  union { float f; u32 u; } v; v.f = f;
  u32 r = v.u + 0x7FFFu + ((v.u >> 16) & 1u);
  return (u16)(r >> 16);
}
__device__ __forceinline__ float bf2f(u16 u) {
  union { u32 u; float f; } v; v.u = ((u32)u) << 16; return v.f;
}
__device__ __forceinline__ float gelu_f(float x) {
  return 0.5f * x * (1.0f + erff(x * 0.70710678118654752f));
}
__device__ __forceinline__ void gl_lds16(const u16* g, u16* l) {
  __builtin_amdgcn_global_load_lds(
      (__attribute__((address_space(1))) void*)(u16*)g,
      (__attribute__((address_space(3))) void*)l, 16, 0, 0);
}

// ---------------- K0: zero stats ----------------
__global__ void k0_zero(float* stats) { stats[threadIdx.x] = 0.0f; }

// ---------------- K1: DWT (interleaved-band semantics) ----------------
// y channel g = subband (g&3) of input channel (g>>2).
// g <  64  -> passthrough to out at (2i,2j), channel g
// g >= 64  -> high[n][g-64]
__global__ __launch_bounds__(256) void k1_dwt(
    const float* __restrict__ x,   // [8][256][256][64]
    u16* __restrict__ high,        // [NPOS][192]
    float* __restrict__ out,       // [8][256][256][64]
    float* __restrict__ stats)     // sum[192], sq[192]
{
  const int blk = blockIdx.x;         // b*128 + i
  const int b = blk >> 7, i = blk & 127;
  const int t = threadIdx.x;
  const int c4 = t & 15;              // input channels c4*4 .. c4*4+3
  const int j0 = t >> 4;              // 0..15
  const int rowE = ((b * 256 + 2 * i) * 256) * 64;
  const int rowO = rowE + 256 * 64;
  const bool isHigh = (c4 >= 4);

  float sacc[16], qacc[16];
#pragma unroll
  for (int v = 0; v < 16; v++) { sacc[v] = 0.f; qacc[v] = 0.f; }

  for (int iter = 0; iter < 8; ++iter) {
    const int j = j0 + 16 * iter;
    const int colE = (2 * j) * 64 + c4 * 4;
    f4 va = *(const f4*)(x + rowE + colE);
    f4 vb = *(const f4*)(x + rowE + colE + 64);
    f4 vc = *(const f4*)(x + rowO + colE);
    f4 vd = *(const f4*)(x + rowO + colE + 64);
    f4 sb0 = (va + vb + vc + vd) * 0.5f;  // LL
    f4 sb1 = (va - vb + vc - vd) * 0.5f;  // LH
    f4 sb2 = (va + vb - vc - vd) * 0.5f;  // HL
    f4 sb3 = (va - vb - vc + vd) * 0.5f;  // HH

    if (!isHigh) {
      // out channels 16*c4 + 4*cc + k  (= 4c+k), position (2i, 2j)
      float* dst = out + rowE + (2 * j) * 64 + 16 * c4;
#pragma unroll
      for (int cc = 0; cc < 4; cc++) {
        f4 ov;
        ov[0] = sb0[cc]; ov[1] = sb1[cc]; ov[2] = sb2[cc]; ov[3] = sb3[cc];
        ((f4*)dst)[cc] = ov;
      }
    } else {
      const int n = b * 16384 + i * 128 + j;
      u16* dst = high + n * 192 + 16 * (c4 - 4);
#pragma unroll
      for (int half = 0; half < 2; half++) {
        u16x8 pk;
#pragma unroll
        for (int cc2 = 0; cc2 < 2; cc2++) {
          const int cc = half * 2 + cc2;
          pk[cc2 * 4 + 0] = f2bf(sb0[cc]);
          pk[cc2 * 4 + 1] = f2bf(sb1[cc]);
          pk[cc2 * 4 + 2] = f2bf(sb2[cc]);
          pk[cc2 * 4 + 3] = f2bf(sb3[cc]);
        }
        *(u16x8*)(dst + half * 8) = pk;
      }
#pragma unroll
      for (int cc = 0; cc < 4; cc++) {
        float e0 = sb0[cc], e1 = sb1[cc], e2 = sb2[cc], e3 = sb3[cc];
        sacc[cc * 4 + 0] += e0; qacc[cc * 4 + 0] += e0 * e0;
        sacc[cc * 4 + 1] += e1; qacc[cc * 4 + 1] += e1 * e1;
        sacc[cc * 4 + 2] += e2; qacc[cc * 4 + 2] += e2 * e2;
        sacc[cc * 4 + 3] += e3; qacc[cc * 4 + 3] += e3 * e3;
      }
    }
  }

  float vals[32];
#pragma unroll
  for (int v = 0; v < 16; v++) { vals[v] = sacc[v]; vals[16 + v] = qacc[v]; }
#pragma unroll
  for (int v = 0; v < 32; v++) {
    float xx = vals[v];
    xx += __shfl_down(xx, 32);
    xx += __shfl_down(xx, 16);
    vals[v] = xx;
  }
  __shared__ float sred[4][12][32];
  const int lane = t & 63, wave = t >> 6;
  if (lane >= 4 && lane < 16) {
#pragma unroll
    for (int v = 0; v < 32; v++) sred[wave][lane - 4][v] = vals[v];
  }
  __syncthreads();
  if (t < 192) {
    const int g = t >> 4, L = t & 15;
    float s = sred[0][g][L] + sred[1][g][L] + sred[2][g][L] + sred[3][g][L];
    float q = sred[0][g][16 + L] + sred[1][g][16 + L] + sred[2][g][16 + L] + sred[3][g][16 + L];
    atomicAdd(&stats[t], s);
    atomicAdd(&stats[192 + t], q);
  }
}

// ---------------- K2a: BN scale/shift ----------------
__global__ void k2a(const float* __restrict__ stats, const float* __restrict__ gamma,
                    const float* __restrict__ beta, float* __restrict__ st)
{
  const int t = threadIdx.x;
  if (t < 192) {
    const float inv_n = 1.0f / 131072.0f;
    float mean = stats[t] * inv_n;
    float var = stats[192 + t] * inv_n - mean * mean;
    var = fmaxf(var, 0.0f);
    float s = gamma[t] * rsqrtf(var + 1e-5f);
    st[t] = s;
    st[192 + t] = beta[t] - mean * s;
  }
}

// ---------------- K2b: fold weights ----------------
__global__ __launch_bounds__(64) void k2b(
    const float* __restrict__ w_in, const float* __restrict__ w_out,
    const float* __restrict__ st, const float* __restrict__ res_scale,
    u16* __restrict__ w_in_f, float* __restrict__ bias1, u16* __restrict__ w_out_f)
{
  const int o = blockIdx.x, lane = threadIdx.x;
  if (o < 384) {
    float p = 0.f;
    for (int c = lane; c < 192; c += 64) {
      float w = w_in[o * 192 + c];
      w_in_f[o * 192 + c] = f2bf(w * st[c]);
      p += w * st[192 + c];
    }
#pragma unroll
    for (int off = 32; off; off >>= 1) p += __shfl_down(p, off);
    if (lane == 0) bias1[o] = p;
  } else {
    const int o2 = o - 384;
    const float rs = res_scale[0];
    for (int c = lane; c < 384; c += 64)
      w_out_f[o2 * 384 + c] = f2bf(w_out[o2 * 384 + c] * rs);
  }
}

// ---------------- K3: GEMM1  h1 = high @ w_in_f^T + bias ----------------
__global__ __launch_bounds__(256) void k3_gemm1(
    const u16* __restrict__ A,   // [Mg][192] bf16
    const u16* __restrict__ Bw,  // [384][192] bf16
    const float* __restrict__ bias,
    u16* __restrict__ C)         // [Mg][384] bf16
{
  __shared__ u16 As[128 * 32];
  __shared__ u16 Bs[128 * 32];
  const int t = threadIdx.x;
  const int lane = t & 63, wave = t >> 6;
  const int wm = wave >> 1, wn = wave & 1;
  const int m0 = blockIdx.x * 128;
  const int n0 = blockIdx.y * 128;
  const int lrow = lane >> 2, lcol = lane & 3;
  const int frow = lane & 15, fk = (lane >> 4) * 8;

  f4 acc[4][4];
#pragma unroll
  for (int a = 0; a < 4; a++)
#pragma unroll
    for (int b = 0; b < 4; b++) acc[a][b] = 0.0f;

  for (int ks = 0; ks < 6; ++ks) {
    const int kb = ks * 32;
#pragma unroll
    for (int l = 0; l < 2; ++l) {
      const int r = wave * 32 + l * 16 + lrow;
      gl_lds16(A + (m0 + r) * 192 + kb + lcol * 8, As + (wave * 32 + l * 16) * 32);
      gl_lds16(Bw + (n0 + r) * 192 + kb + lcol * 8, Bs + (wave * 32 + l * 16) * 32);
    }
    __syncthreads();
    bf8 af[4], bfr[4];
#pragma unroll
    for (int fm = 0; fm < 4; ++fm)
      af[fm] = *(const bf8*)(As + (wm * 64 + fm * 16 + frow) * 32 + fk);
#pragma unroll
    for (int fn = 0; fn < 4; ++fn)
      bfr[fn] = *(const bf8*)(Bs + (wn * 64 + fn * 16 + frow) * 32 + fk);
#pragma unroll
    for (int fm = 0; fm < 4; ++fm)
#pragma unroll
      for (int fn = 0; fn < 4; ++fn)
        acc[fm][fn] = __builtin_amdgcn_mfma_f32_16x16x32_bf16(af[fm], bfr[fn], acc[fm][fn], 0, 0, 0);
    __syncthreads();
  }
  const int r0 = (lane >> 4) * 4, cc = lane & 15;
#pragma unroll
  for (int fn = 0; fn < 4; ++fn) {
    const int col = n0 + wn * 64 + fn * 16 + cc;
    const float bv = bias[col];
#pragma unroll
    for (int fm = 0; fm < 4; ++fm) {
      const int mrow = m0 + wm * 64 + fm * 16 + r0;
#pragma unroll
      for (int r = 0; r < 4; ++r)
        C[(mrow + r) * 384 + col] = f2bf(acc[fm][fn][r] + bv);
    }
  }
}

// ---------------- K4: depthwise 3x3 + GELU ----------------
__global__ __launch_bounds__(384) void k4_dw(
    const u16* __restrict__ h1,   // [Mg][384]
    const float* __restrict__ wdw, // [384*9]
    u16* __restrict__ h2)         // [Mg][384]
{
  const int row = blockIdx.x;      // bl*128 + i
  const int bl = row >> 7, i = row & 127;
  const int t = threadIdx.x;
  const int cg = t % 48, j0 = t / 48;
  const int c0 = cg * 8;
  float w[8][9];
#pragma unroll
  for (int cc = 0; cc < 8; cc++)
#pragma unroll
    for (int k = 0; k < 9; k++) w[cc][k] = wdw[(c0 + cc) * 9 + k];
  const int ibase = bl * 16384;

  for (int iter = 0; iter < 16; ++iter) {
    const int j = j0 + 8 * iter;
    float acc[8];
#pragma unroll
    for (int cc = 0; cc < 8; cc++) acc[cc] = 0.f;
#pragma unroll
    for (int dy = -1; dy <= 1; dy++) {
      const int ii = i + dy;
      if (ii < 0 || ii > 127) continue;
#pragma unroll
      for (int dx = -1; dx <= 1; dx++) {
        const int jj = j + dx;
        if (jj < 0 || jj > 127) continue;
        const u16x8 v = *(const u16x8*)(h1 + (ibase + ii * 128 + jj) * 384 + c0);
        const int k = (dy + 1) * 3 + (dx + 1);
#pragma unroll
        for (int cc = 0; cc < 8; cc++) acc[cc] += w[cc][k] * bf2f(v[cc]);
      }
    }
    u16x8 o;
#pragma unroll
    for (int cc = 0; cc < 8; cc++) o[cc] = f2bf(gelu_f(acc[cc]));
    *(u16x8*)(h2 + (ibase + i * 128 + j) * 384 + c0) = o;
  }
}

// ---------------- K5: GEMM2 + residual + interleave scatter ----------------
__global__ __launch_bounds__(256) void k5_gemm2(
    const u16* __restrict__ A,     // h2 [Mg][384]
    const u16* __restrict__ Bw,    // [192][384]
    const u16* __restrict__ high,  // [NPOS][192]
    float* __restrict__ out,       // [8][256][256][64]
    int chunkStart)
{
  __shared__ u16 As[128 * 32];
  __shared__ u16 Bs[192 * 32];
  const int t = threadIdx.x;
  const int lane = t & 63, wave = t >> 6;
  const int wm = wave >> 1, wn = wave & 1;
  const int m0 = blockIdx.x * 128;
  const int lrow = lane >> 2, lcol = lane & 3;
  const int frow = lane & 15, fk = (lane >> 4) * 8;

  f4 acc[4][6];
#pragma unroll
  for (int a = 0; a < 4; a++)
#pragma unroll
    for (int b = 0; b < 6; b++) acc[a][b] = 0.0f;

  for (int ks = 0; ks < 12; ++ks) {
    const int kb = ks * 32;
#pragma unroll
    for (int l = 0; l < 2; ++l) {
      const int r = wave * 32 + l * 16 + lrow;
      gl_lds16(A + (m0 + r) * 384 + kb + lcol * 8, As + (wave * 32 + l * 16) * 32);
    }
#pragma unroll
    for (int l = 0; l < 3; ++l) {
      const int rb = wave * 48 + l * 16 + lrow;
      gl_lds16(Bw + rb * 384 + kb + lcol * 8, Bs + (wave * 48 + l * 16) * 32);
    }
    __syncthreads();
    bf8 af[4], bfr[6];
#pragma unroll
    for (int fm = 0; fm < 4; ++fm)
      af[fm] = *(const bf8*)(As + (wm * 64 + fm * 16 + frow) * 32 + fk);
#pragma unroll
    for (int fn = 0; fn < 6; ++fn)
      bfr[fn] = *(const bf8*)(Bs + (wn * 96 + fn * 16 + frow) * 32 + fk);
#pragma unroll
    for (int fm = 0; fm < 4; ++fm)
#pragma unroll
      for (int fn = 0; fn < 6; ++fn)
        acc[fm][fn] = __builtin_amdgcn_mfma_f32_16x16x32_bf16(af[fm], bfr[fn], acc[fm][fn], 0, 0, 0);
    __syncthreads();
  }

  // high channel h -> output block s = h/64 + 1 at (2i+p, 2j+q), channel h&63
  const int r0 = (lane >> 4) * 4, ccol = lane & 15;
#pragma unroll
  for (int fn = 0; fn < 6; ++fn) {
    const int oc = wn * 96 + fn * 16 + ccol;
    const int band = oc >> 6, c = oc & 63;
    const int p = (band + 1) >> 1, q = (band + 1) & 1;
#pragma unroll
    for (int fm = 0; fm < 4; ++fm) {
#pragma unroll
      for (int r = 0; r < 4; ++r) {
        const int m = m0 + wm * 64 + fm * 16 + r0 + r;
        const int np = chunkStart + m;
        const int b = np >> 14, rem = np & 16383, i = rem >> 7, j = rem & 127;
        const float hv = bf2f(high[np * 192 + oc]);
        out[((b * 256 + 2 * i + p) * 256 + (2 * j + q)) * 64 + c] = hv + acc[fm][fn][r];
      }
    }
  }
}

extern "C" void kernel_launch(void* const* d_in, const int* in_sizes, int n_in,
                              void* d_out, int out_size, void* d_ws, size_t ws_size,
                              hipStream_t stream)
{
  const float* x        = (const float*)d_in[0];
  const float* gamma    = (const float*)d_in[1];
  const float* beta     = (const float*)d_in[2];
  const float* w_in     = (const float*)d_in[3];
  const float* w_dw     = (const float*)d_in[4];
  const float* w_out    = (const float*)d_in[5];
  const float* res_scale= (const float*)d_in[6];
  float* out = (float*)d_out;
  char* ws = (char*)d_ws;

  float* stats   = (float*)ws;                     // 384 floats
  float* st      = (float*)(ws + 2048);            // 384 floats
  float* bias1   = (float*)(ws + 4096);            // 384 floats
  u16*   w_in_f  = (u16*)(ws + 8192);              // 147456 B
  u16*   w_out_f = (u16*)(ws + 8192 + 147456);     // 147456 B
  u16*   high    = (u16*)(ws + (size_t)(1 << 19)); // 50331648 B
  const size_t off_h1 = (size_t)(1 << 19) + (size_t)NPOS * 192 * 2;
  const size_t imgBytes = (size_t)16384 * 384 * 2; // 12582912 per image per buffer
  int G = 8;
  while (G > 1 && off_h1 + 2 * (size_t)G * imgBytes > ws_size) G >>= 1;
  u16* h1 = (u16*)(ws + off_h1);
  u16* h2 = (u16*)(ws + off_h1 + (size_t)G * imgBytes);

  k0_zero<<<1, 384, 0, stream>>>(stats);
  k1_dwt<<<1024, 256, 0, stream>>>(x, high, out, stats);
  k2a<<<1, 256, 0, stream>>>(stats, gamma, beta, st);
  k2b<<<576, 64, 0, stream>>>(w_in, w_out, st, res_scale, w_in_f, bias1, w_out_f);

  for (int cs = 0; cs < 8; cs += G) {
    const int chunkStart = cs * 16384;
    const int Mg = G * 16384;
    k3_gemm1<<<dim3(Mg / 128, 3), 256, 0, stream>>>(high + (size_t)chunkStart * 192, w_in_f, bias1, h1);
    k4_dw<<<G * 128, 384, 0, stream>>>(h1, w_dw, h2);
    k5_gemm2<<<dim3(Mg / 128, 1), 256, 0, stream>>>(h2, w_out_f, high, out, chunkStart);
  }
}

// Round 3
// 523.422 us; speedup vs baseline: 1.0881x; 1.0881x over previous
//
#include <hip/hip_runtime.h>
#include <math.h>

typedef unsigned short u16;
typedef unsigned int u32;
typedef __attribute__((ext_vector_type(4))) float f4;
typedef __attribute__((ext_vector_type(4))) u16 u16x4;
typedef __attribute__((ext_vector_type(8))) u16 u16x8;
typedef __attribute__((ext_vector_type(8))) short bf8;

#define N_IMG 8
#define HS 128               // half spatial
#define NPOS (N_IMG*HS*HS)   // 131072
#define IN_CH 192
#define HID_CH 384

__device__ __forceinline__ u16 f2bf(float f) {
  union { float f; u32 u; } v; v.f = f;
  u32 r = v.u + 0x7FFFu + ((v.u >> 16) & 1u);
  return (u16)(r >> 16);
}
__device__ __forceinline__ float bf2f(u16 u) {
  union { u32 u; float f; } v; v.u = ((u32)u) << 16; return v.f;
}
__device__ __forceinline__ float gelu_f(float x) {
  return 0.5f * x * (1.0f + erff(x * 0.70710678118654752f));
}
__device__ __forceinline__ void gl_lds16(const u16* g, u16* l) {
  __builtin_amdgcn_global_load_lds(
      (__attribute__((address_space(1))) void*)(u16*)g,
      (__attribute__((address_space(3))) void*)l, 16, 0, 0);
}

// ---------------- K0: zero stats ----------------
__global__ void k0_zero(float* stats) { stats[threadIdx.x] = 0.0f; }

// ---------------- K1: DWT (interleaved-band semantics) ----------------
__global__ __launch_bounds__(256) void k1_dwt(
    const float* __restrict__ x,   // [8][256][256][64]
    u16* __restrict__ high,        // [NPOS][192]
    float* __restrict__ out,       // [8][256][256][64]
    float* __restrict__ stats)     // sum[192], sq[192]
{
  const int blk = blockIdx.x;         // b*128 + i
  const int b = blk >> 7, i = blk & 127;
  const int t = threadIdx.x;
  const int c4 = t & 15;              // input channels c4*4 .. c4*4+3
  const int j0 = t >> 4;              // 0..15
  const int rowE = ((b * 256 + 2 * i) * 256) * 64;
  const int rowO = rowE + 256 * 64;
  const bool isHigh = (c4 >= 4);

  float sacc[16], qacc[16];
#pragma unroll
  for (int v = 0; v < 16; v++) { sacc[v] = 0.f; qacc[v] = 0.f; }

  for (int iter = 0; iter < 8; ++iter) {
    const int j = j0 + 16 * iter;
    const int colE = (2 * j) * 64 + c4 * 4;
    f4 va = *(const f4*)(x + rowE + colE);
    f4 vb = *(const f4*)(x + rowE + colE + 64);
    f4 vc = *(const f4*)(x + rowO + colE);
    f4 vd = *(const f4*)(x + rowO + colE + 64);
    f4 sb0 = (va + vb + vc + vd) * 0.5f;  // LL
    f4 sb1 = (va - vb + vc - vd) * 0.5f;  // LH
    f4 sb2 = (va + vb - vc - vd) * 0.5f;  // HL
    f4 sb3 = (va - vb - vc + vd) * 0.5f;  // HH

    if (!isHigh) {
      float* dst = out + rowE + (2 * j) * 64 + 16 * c4;
#pragma unroll
      for (int cc = 0; cc < 4; cc++) {
        f4 ov;
        ov[0] = sb0[cc]; ov[1] = sb1[cc]; ov[2] = sb2[cc]; ov[3] = sb3[cc];
        ((f4*)dst)[cc] = ov;
      }
    } else {
      const int n = b * 16384 + i * 128 + j;
      u16* dst = high + n * 192 + 16 * (c4 - 4);
#pragma unroll
      for (int half = 0; half < 2; half++) {
        u16x8 pk;
#pragma unroll
        for (int cc2 = 0; cc2 < 2; cc2++) {
          const int cc = half * 2 + cc2;
          pk[cc2 * 4 + 0] = f2bf(sb0[cc]);
          pk[cc2 * 4 + 1] = f2bf(sb1[cc]);
          pk[cc2 * 4 + 2] = f2bf(sb2[cc]);
          pk[cc2 * 4 + 3] = f2bf(sb3[cc]);
        }
        *(u16x8*)(dst + half * 8) = pk;
      }
#pragma unroll
      for (int cc = 0; cc < 4; cc++) {
        float e0 = sb0[cc], e1 = sb1[cc], e2 = sb2[cc], e3 = sb3[cc];
        sacc[cc * 4 + 0] += e0; qacc[cc * 4 + 0] += e0 * e0;
        sacc[cc * 4 + 1] += e1; qacc[cc * 4 + 1] += e1 * e1;
        sacc[cc * 4 + 2] += e2; qacc[cc * 4 + 2] += e2 * e2;
        sacc[cc * 4 + 3] += e3; qacc[cc * 4 + 3] += e3 * e3;
      }
    }
  }

  float vals[32];
#pragma unroll
  for (int v = 0; v < 16; v++) { vals[v] = sacc[v]; vals[16 + v] = qacc[v]; }
#pragma unroll
  for (int v = 0; v < 32; v++) {
    float xx = vals[v];
    xx += __shfl_down(xx, 32);
    xx += __shfl_down(xx, 16);
    vals[v] = xx;
  }
  __shared__ float sred[4][12][32];
  const int lane = t & 63, wave = t >> 6;
  if (lane >= 4 && lane < 16) {
#pragma unroll
    for (int v = 0; v < 32; v++) sred[wave][lane - 4][v] = vals[v];
  }
  __syncthreads();
  if (t < 192) {
    const int g = t >> 4, L = t & 15;
    float s = sred[0][g][L] + sred[1][g][L] + sred[2][g][L] + sred[3][g][L];
    float q = sred[0][g][16 + L] + sred[1][g][16 + L] + sred[2][g][16 + L] + sred[3][g][16 + L];
    atomicAdd(&stats[t], s);
    atomicAdd(&stats[192 + t], q);
  }
}

// ---------------- K2a: BN scale/shift ----------------
__global__ void k2a(const float* __restrict__ stats, const float* __restrict__ gamma,
                    const float* __restrict__ beta, float* __restrict__ st)
{
  const int t = threadIdx.x;
  if (t < 192) {
    const float inv_n = 1.0f / 131072.0f;
    float mean = stats[t] * inv_n;
    float var = stats[192 + t] * inv_n - mean * mean;
    var = fmaxf(var, 0.0f);
    float s = gamma[t] * rsqrtf(var + 1e-5f);
    st[t] = s;
    st[192 + t] = beta[t] - mean * s;
  }
}

// ---------------- K2b: fold weights ----------------
__global__ __launch_bounds__(64) void k2b(
    const float* __restrict__ w_in, const float* __restrict__ w_out,
    const float* __restrict__ st, const float* __restrict__ res_scale,
    u16* __restrict__ w_in_f, float* __restrict__ bias1, u16* __restrict__ w_out_f)
{
  const int o = blockIdx.x, lane = threadIdx.x;
  if (o < 384) {
    float p = 0.f;
    for (int c = lane; c < 192; c += 64) {
      float w = w_in[o * 192 + c];
      w_in_f[o * 192 + c] = f2bf(w * st[c]);
      p += w * st[192 + c];
    }
#pragma unroll
    for (int off = 32; off; off >>= 1) p += __shfl_down(p, off);
    if (lane == 0) bias1[o] = p;
  } else {
    const int o2 = o - 384;
    const float rs = res_scale[0];
    for (int c = lane; c < 384; c += 64)
      w_out_f[o2 * 384 + c] = f2bf(w_out[o2 * 384 + c] * rs);
  }
}

// ---------------- K3: GEMM1  h1 = high @ w_in_f^T + bias ----------------
__global__ __launch_bounds__(256) void k3_gemm1(
    const u16* __restrict__ A,   // [Mg][192] bf16
    const u16* __restrict__ Bw,  // [384][192] bf16
    const float* __restrict__ bias,
    u16* __restrict__ C)         // [Mg][384] bf16
{
  __shared__ u16 As[128 * 32];
  __shared__ u16 Bs[128 * 32];
  const int t = threadIdx.x;
  const int lane = t & 63, wave = t >> 6;
  const int wm = wave >> 1, wn = wave & 1;
  const int m0 = blockIdx.x * 128;
  const int n0 = blockIdx.y * 128;
  const int lrow = lane >> 2, lcol = lane & 3;
  const int frow = lane & 15, fk = (lane >> 4) * 8;

  f4 acc[4][4];
#pragma unroll
  for (int a = 0; a < 4; a++)
#pragma unroll
    for (int b = 0; b < 4; b++) acc[a][b] = 0.0f;

  for (int ks = 0; ks < 6; ++ks) {
    const int kb = ks * 32;
#pragma unroll
    for (int l = 0; l < 2; ++l) {
      const int r = wave * 32 + l * 16 + lrow;
      gl_lds16(A + (m0 + r) * 192 + kb + lcol * 8, As + (wave * 32 + l * 16) * 32);
      gl_lds16(Bw + (n0 + r) * 192 + kb + lcol * 8, Bs + (wave * 32 + l * 16) * 32);
    }
    __syncthreads();
    bf8 af[4], bfr[4];
#pragma unroll
    for (int fm = 0; fm < 4; ++fm)
      af[fm] = *(const bf8*)(As + (wm * 64 + fm * 16 + frow) * 32 + fk);
#pragma unroll
    for (int fn = 0; fn < 4; ++fn)
      bfr[fn] = *(const bf8*)(Bs + (wn * 64 + fn * 16 + frow) * 32 + fk);
#pragma unroll
    for (int fm = 0; fm < 4; ++fm)
#pragma unroll
      for (int fn = 0; fn < 4; ++fn)
        acc[fm][fn] = __builtin_amdgcn_mfma_f32_16x16x32_bf16(af[fm], bfr[fn], acc[fm][fn], 0, 0, 0);
    __syncthreads();
  }
  const int r0 = (lane >> 4) * 4, cc = lane & 15;
#pragma unroll
  for (int fn = 0; fn < 4; ++fn) {
    const int col = n0 + wn * 64 + fn * 16 + cc;
    const float bv = bias[col];
#pragma unroll
    for (int fm = 0; fm < 4; ++fm) {
      const int mrow = m0 + wm * 64 + fm * 16 + r0;
#pragma unroll
      for (int r = 0; r < 4; ++r)
        C[(mrow + r) * 384 + col] = f2bf(acc[fm][fn][r] + bv);
    }
  }
}

// ---------------- K4: depthwise 3x3 + GELU, sliding-row window ----------------
// block: 384 threads = 8 columns (jl) x 48 channel-groups (cg, 8 ch each)
// covers one (img, row-tile of 16, j-tile of 8); iterates rows r0-1 .. r0+16
// per row: 1 global load -> LDS ring (2 slots), share j+-1 via LDS,
// P_k(r,j) = horizontal conv with weight row k; out(i) = P0(i-1)+P1(i)+P2(i+1)
#define K4_ROWS 16
__global__ __launch_bounds__(384) void k4_dw(
    const u16* __restrict__ h1,    // [Mg][384]
    const float* __restrict__ wdw, // [384*9]
    u16* __restrict__ h2)          // [Mg][384]
{
  const int blk = blockIdx.x;
  const int jt  = blk & 15;
  const int rt  = (blk >> 4) & 7;
  const int img = blk >> 7;
  const int t = threadIdx.x;
  const int jl = t / 48;           // 0..7
  const int cg = t % 48;
  const int c0 = cg * 8;
  const int jg = jt * 8 + jl;
  const int ibase = img * 16384;
  const int r0 = rt * K4_ROWS;

  float w[3][3][8];
#pragma unroll
  for (int dy = 0; dy < 3; dy++)
#pragma unroll
    for (int dx = 0; dx < 3; dx++)
#pragma unroll
      for (int ch = 0; ch < 8; ch++)
        w[dy][dx][ch] = wdw[(c0 + ch) * 9 + dy * 3 + dx];

  __shared__ u16 ring[2][10][48 * 8];   // [slot][j(-1..8)+1][cg*8+ch]

  float accA[8], accB[8];
#pragma unroll
  for (int ch = 0; ch < 8; ch++) { accA[ch] = 0.f; accB[ch] = 0.f; }

  const u16x8 zero8 = (u16x8)(0);

  for (int r = r0 - 1; r <= r0 + K4_ROWS; ++r) {
    const int slot = r & 1;
    const bool rowOK = (r >= 0 && r < 128);
    u16x8 v = zero8;
    if (rowOK) v = *(const u16x8*)(h1 + (size_t)(ibase + r * 128 + jg) * 384 + c0);
    *(u16x8*)&ring[slot][jl + 1][c0] = v;
    if (jl == 0) {
      u16x8 hv = zero8;
      if (rowOK && jg - 1 >= 0) hv = *(const u16x8*)(h1 + (size_t)(ibase + r * 128 + jg - 1) * 384 + c0);
      *(u16x8*)&ring[slot][0][c0] = hv;
    }
    if (jl == 7) {
      u16x8 hv = zero8;
      if (rowOK && jg + 1 < 128) hv = *(const u16x8*)(h1 + (size_t)(ibase + r * 128 + jg + 1) * 384 + c0);
      *(u16x8*)&ring[slot][9][c0] = hv;
    }
    __syncthreads();
    const u16x8 vm = *(const u16x8*)&ring[slot][jl][c0];
    const u16x8 v0 = *(const u16x8*)&ring[slot][jl + 1][c0];
    const u16x8 vp = *(const u16x8*)&ring[slot][jl + 2][c0];

    float P0[8], P1[8], P2[8];
#pragma unroll
    for (int ch = 0; ch < 8; ch++) {
      const float fm = bf2f(vm[ch]);
      const float f0 = bf2f(v0[ch]);
      const float fp = bf2f(vp[ch]);
      P0[ch] = w[0][0][ch] * fm + w[0][1][ch] * f0 + w[0][2][ch] * fp;
      P1[ch] = w[1][0][ch] * fm + w[1][1][ch] * f0 + w[1][2][ch] * fp;
      P2[ch] = w[2][0][ch] * fm + w[2][1][ch] * f0 + w[2][2][ch] * fp;
    }
    if (r >= r0 + 1) {   // emit out row r-1 (in [r0, r0+15])
      u16x8 o;
#pragma unroll
      for (int ch = 0; ch < 8; ch++)
        o[ch] = f2bf(gelu_f(accA[ch] + P2[ch]));
      *(u16x8*)(h2 + (size_t)(ibase + (r - 1) * 128 + jg) * 384 + c0) = o;
    }
#pragma unroll
    for (int ch = 0; ch < 8; ch++) {
      accA[ch] = accB[ch] + P1[ch];
      accB[ch] = P0[ch];
    }
  }
}

// ---------------- K5: GEMM2 + residual + interleave scatter ----------------
__global__ __launch_bounds__(256) void k5_gemm2(
    const u16* __restrict__ A,     // h2 [Mg][384]
    const u16* __restrict__ Bw,    // [192][384]
    const u16* __restrict__ high,  // [NPOS][192]
    float* __restrict__ out,       // [8][256][256][64]
    int chunkStart)
{
  __shared__ u16 As[128 * 32];
  __shared__ u16 Bs[192 * 32];
  const int t = threadIdx.x;
  const int lane = t & 63, wave = t >> 6;
  const int wm = wave >> 1, wn = wave & 1;
  const int m0 = blockIdx.x * 128;
  const int lrow = lane >> 2, lcol = lane & 3;
  const int frow = lane & 15, fk = (lane >> 4) * 8;

  f4 acc[4][6];
#pragma unroll
  for (int a = 0; a < 4; a++)
#pragma unroll
    for (int b = 0; b < 6; b++) acc[a][b] = 0.0f;

  for (int ks = 0; ks < 12; ++ks) {
    const int kb = ks * 32;
#pragma unroll
    for (int l = 0; l < 2; ++l) {
      const int r = wave * 32 + l * 16 + lrow;
      gl_lds16(A + (m0 + r) * 384 + kb + lcol * 8, As + (wave * 32 + l * 16) * 32);
    }
#pragma unroll
    for (int l = 0; l < 3; ++l) {
      const int rb = wave * 48 + l * 16 + lrow;
      gl_lds16(Bw + rb * 384 + kb + lcol * 8, Bs + (wave * 48 + l * 16) * 32);
    }
    __syncthreads();
    bf8 af[4], bfr[6];
#pragma unroll
    for (int fm = 0; fm < 4; ++fm)
      af[fm] = *(const bf8*)(As + (wm * 64 + fm * 16 + frow) * 32 + fk);
#pragma unroll
    for (int fn = 0; fn < 6; ++fn)
      bfr[fn] = *(const bf8*)(Bs + (wn * 96 + fn * 16 + frow) * 32 + fk);
#pragma unroll
    for (int fm = 0; fm < 4; ++fm)
#pragma unroll
      for (int fn = 0; fn < 6; ++fn)
        acc[fm][fn] = __builtin_amdgcn_mfma_f32_16x16x32_bf16(af[fm], bfr[fn], acc[fm][fn], 0, 0, 0);
    __syncthreads();
  }

  const int r0 = (lane >> 4) * 4, ccol = lane & 15;
#pragma unroll
  for (int fn = 0; fn < 6; ++fn) {
    const int oc = wn * 96 + fn * 16 + ccol;
    const int band = oc >> 6, c = oc & 63;
    const int p = (band + 1) >> 1, q = (band + 1) & 1;
#pragma unroll
    for (int fm = 0; fm < 4; ++fm) {
#pragma unroll
      for (int r = 0; r < 4; ++r) {
        const int m = m0 + wm * 64 + fm * 16 + r0 + r;
        const int np = chunkStart + m;
        const int b = np >> 14, rem = np & 16383, i = rem >> 7, j = rem & 127;
        const float hv = bf2f(high[np * 192 + oc]);
        out[((b * 256 + 2 * i + p) * 256 + (2 * j + q)) * 64 + c] = hv + acc[fm][fn][r];
      }
    }
  }
}

extern "C" void kernel_launch(void* const* d_in, const int* in_sizes, int n_in,
                              void* d_out, int out_size, void* d_ws, size_t ws_size,
                              hipStream_t stream)
{
  const float* x        = (const float*)d_in[0];
  const float* gamma    = (const float*)d_in[1];
  const float* beta     = (const float*)d_in[2];
  const float* w_in     = (const float*)d_in[3];
  const float* w_dw     = (const float*)d_in[4];
  const float* w_out    = (const float*)d_in[5];
  const float* res_scale= (const float*)d_in[6];
  float* out = (float*)d_out;
  char* ws = (char*)d_ws;

  float* stats   = (float*)ws;                     // 384 floats
  float* st      = (float*)(ws + 2048);            // 384 floats
  float* bias1   = (float*)(ws + 4096);            // 384 floats
  u16*   w_in_f  = (u16*)(ws + 8192);              // 147456 B
  u16*   w_out_f = (u16*)(ws + 8192 + 147456);     // 147456 B
  u16*   high    = (u16*)(ws + (size_t)(1 << 19)); // 50331648 B
  const size_t off_h1 = (size_t)(1 << 19) + (size_t)NPOS * 192 * 2;
  const size_t imgBytes = (size_t)16384 * 384 * 2; // 12582912 per image per buffer
  int G = 8;
  while (G > 1 && off_h1 + 2 * (size_t)G * imgBytes > ws_size) G >>= 1;
  u16* h1 = (u16*)(ws + off_h1);
  u16* h2 = (u16*)(ws + off_h1 + (size_t)G * imgBytes);

  k0_zero<<<1, 384, 0, stream>>>(stats);
  k1_dwt<<<1024, 256, 0, stream>>>(x, high, out, stats);
  k2a<<<1, 256, 0, stream>>>(stats, gamma, beta, st);
  k2b<<<576, 64, 0, stream>>>(w_in, w_out, st, res_scale, w_in_f, bias1, w_out_f);

  for (int cs = 0; cs < 8; cs += G) {
    const int chunkStart = cs * 16384;
    const int Mg = G * 16384;
    k3_gemm1<<<dim3(Mg / 128, 3), 256, 0, stream>>>(high + (size_t)chunkStart * 192, w_in_f, bias1, h1);
    k4_dw<<<G * 128, 384, 0, stream>>>(h1, w_dw, h2);
    k5_gemm2<<<dim3(Mg / 128, 1), 256, 0, stream>>>(h2, w_out_f, high, out, chunkStart);
  }
}

// Round 4
// 438.501 us; speedup vs baseline: 1.2988x; 1.1937x over previous
//
#include <hip/hip_runtime.h>
#include <math.h>

typedef unsigned short u16;
typedef unsigned int u32;
typedef __attribute__((ext_vector_type(4))) float f4;
typedef __attribute__((ext_vector_type(2))) float f2;
typedef __attribute__((ext_vector_type(4))) u16 u16x4;
typedef __attribute__((ext_vector_type(8))) u16 u16x8;
typedef __attribute__((ext_vector_type(8))) short bf8;

#define N_IMG 8
#define HS 128               // half spatial
#define NPOS (N_IMG*HS*HS)   // 131072
#define IN_CH 192
#define HID_CH 384

__device__ __forceinline__ u16 f2bf(float f) {
  union { float f; u32 u; } v; v.f = f;
  u32 r = v.u + 0x7FFFu + ((v.u >> 16) & 1u);
  return (u16)(r >> 16);
}
__device__ __forceinline__ float bf2f(u16 u) {
  union { u32 u; float f; } v; v.u = ((u32)u) << 16; return v.f;
}
// f2 pair from one dword holding two bf16 (even=low half, odd=high half)
__device__ __forceinline__ f2 bfpair(u32 d) {
  union { u32 u; float f; } lo, hi;
  lo.u = d << 16; hi.u = d & 0xffff0000u;
  f2 r; r[0] = lo.f; r[1] = hi.f; return r;
}
// gelu(x) = x * sigmoid(1.595769122x + 0.071354816x^3)  (tanh-form, exact identity)
// = x * rcp(1 + exp2(x*(-2.302208 - 0.102942*x^2)))
__device__ __forceinline__ float gelu_fast(float x) {
  float x2 = x * x;
  float z = x * (-2.302208f - 0.102942f * x2);
  float e = __builtin_amdgcn_exp2f(z);
  return x * __builtin_amdgcn_rcpf(1.0f + e);
}
__device__ __forceinline__ void gl_lds16(const u16* g, u16* l) {
  __builtin_amdgcn_global_load_lds(
      (__attribute__((address_space(1))) void*)(u16*)g,
      (__attribute__((address_space(3))) void*)l, 16, 0, 0);
}

// ---------------- K0: zero stats ----------------
__global__ void k0_zero(float* stats) { stats[threadIdx.x] = 0.0f; }

// ---------------- K1: DWT (interleaved-band semantics) ----------------
__global__ __launch_bounds__(256) void k1_dwt(
    const float* __restrict__ x,   // [8][256][256][64]
    u16* __restrict__ high,        // [NPOS][192]
    float* __restrict__ out,       // [8][256][256][64]
    float* __restrict__ stats)     // sum[192], sq[192]
{
  const int blk = blockIdx.x;         // b*128 + i
  const int b = blk >> 7, i = blk & 127;
  const int t = threadIdx.x;
  const int c4 = t & 15;              // input channels c4*4 .. c4*4+3
  const int j0 = t >> 4;              // 0..15
  const int rowE = ((b * 256 + 2 * i) * 256) * 64;
  const int rowO = rowE + 256 * 64;
  const bool isHigh = (c4 >= 4);

  float sacc[16], qacc[16];
#pragma unroll
  for (int v = 0; v < 16; v++) { sacc[v] = 0.f; qacc[v] = 0.f; }

  for (int iter = 0; iter < 8; ++iter) {
    const int j = j0 + 16 * iter;
    const int colE = (2 * j) * 64 + c4 * 4;
    f4 va = *(const f4*)(x + rowE + colE);
    f4 vb = *(const f4*)(x + rowE + colE + 64);
    f4 vc = *(const f4*)(x + rowO + colE);
    f4 vd = *(const f4*)(x + rowO + colE + 64);
    f4 sb0 = (va + vb + vc + vd) * 0.5f;  // LL
    f4 sb1 = (va - vb + vc - vd) * 0.5f;  // LH
    f4 sb2 = (va + vb - vc - vd) * 0.5f;  // HL
    f4 sb3 = (va - vb - vc + vd) * 0.5f;  // HH

    if (!isHigh) {
      float* dst = out + rowE + (2 * j) * 64 + 16 * c4;
#pragma unroll
      for (int cc = 0; cc < 4; cc++) {
        f4 ov;
        ov[0] = sb0[cc]; ov[1] = sb1[cc]; ov[2] = sb2[cc]; ov[3] = sb3[cc];
        ((f4*)dst)[cc] = ov;
      }
    } else {
      const int n = b * 16384 + i * 128 + j;
      u16* dst = high + n * 192 + 16 * (c4 - 4);
#pragma unroll
      for (int half = 0; half < 2; half++) {
        u16x8 pk;
#pragma unroll
        for (int cc2 = 0; cc2 < 2; cc2++) {
          const int cc = half * 2 + cc2;
          pk[cc2 * 4 + 0] = f2bf(sb0[cc]);
          pk[cc2 * 4 + 1] = f2bf(sb1[cc]);
          pk[cc2 * 4 + 2] = f2bf(sb2[cc]);
          pk[cc2 * 4 + 3] = f2bf(sb3[cc]);
        }
        *(u16x8*)(dst + half * 8) = pk;
      }
#pragma unroll
      for (int cc = 0; cc < 4; cc++) {
        float e0 = sb0[cc], e1 = sb1[cc], e2 = sb2[cc], e3 = sb3[cc];
        sacc[cc * 4 + 0] += e0; qacc[cc * 4 + 0] += e0 * e0;
        sacc[cc * 4 + 1] += e1; qacc[cc * 4 + 1] += e1 * e1;
        sacc[cc * 4 + 2] += e2; qacc[cc * 4 + 2] += e2 * e2;
        sacc[cc * 4 + 3] += e3; qacc[cc * 4 + 3] += e3 * e3;
      }
    }
  }

  float vals[32];
#pragma unroll
  for (int v = 0; v < 16; v++) { vals[v] = sacc[v]; vals[16 + v] = qacc[v]; }
#pragma unroll
  for (int v = 0; v < 32; v++) {
    float xx = vals[v];
    xx += __shfl_down(xx, 32);
    xx += __shfl_down(xx, 16);
    vals[v] = xx;
  }
  __shared__ float sred[4][12][32];
  const int lane = t & 63, wave = t >> 6;
  if (lane >= 4 && lane < 16) {
#pragma unroll
    for (int v = 0; v < 32; v++) sred[wave][lane - 4][v] = vals[v];
  }
  __syncthreads();
  if (t < 192) {
    const int g = t >> 4, L = t & 15;
    float s = sred[0][g][L] + sred[1][g][L] + sred[2][g][L] + sred[3][g][L];
    float q = sred[0][g][16 + L] + sred[1][g][16 + L] + sred[2][g][16 + L] + sred[3][g][16 + L];
    atomicAdd(&stats[t], s);
    atomicAdd(&stats[192 + t], q);
  }
}

// ---------------- K2a: BN scale/shift ----------------
__global__ void k2a(const float* __restrict__ stats, const float* __restrict__ gamma,
                    const float* __restrict__ beta, float* __restrict__ st)
{
  const int t = threadIdx.x;
  if (t < 192) {
    const float inv_n = 1.0f / 131072.0f;
    float mean = stats[t] * inv_n;
    float var = stats[192 + t] * inv_n - mean * mean;
    var = fmaxf(var, 0.0f);
    float s = gamma[t] * rsqrtf(var + 1e-5f);
    st[t] = s;
    st[192 + t] = beta[t] - mean * s;
  }
}

// ---------------- K2b: fold weights ----------------
__global__ __launch_bounds__(64) void k2b(
    const float* __restrict__ w_in, const float* __restrict__ w_out,
    const float* __restrict__ st, const float* __restrict__ res_scale,
    u16* __restrict__ w_in_f, float* __restrict__ bias1, u16* __restrict__ w_out_f)
{
  const int o = blockIdx.x, lane = threadIdx.x;
  if (o < 384) {
    float p = 0.f;
    for (int c = lane; c < 192; c += 64) {
      float w = w_in[o * 192 + c];
      w_in_f[o * 192 + c] = f2bf(w * st[c]);
      p += w * st[192 + c];
    }
#pragma unroll
    for (int off = 32; off; off >>= 1) p += __shfl_down(p, off);
    if (lane == 0) bias1[o] = p;
  } else {
    const int o2 = o - 384;
    const float rs = res_scale[0];
    for (int c = lane; c < 384; c += 64)
      w_out_f[o2 * 384 + c] = f2bf(w_out[o2 * 384 + c] * rs);
  }
}

// ---------------- K3: GEMM1  h1 = high @ w_in_f^T + bias ----------------
// h1 layout: [2][Mg][192] (channel halves split)
__global__ __launch_bounds__(256) void k3_gemm1(
    const u16* __restrict__ A,   // [Mg][192] bf16
    const u16* __restrict__ Bw,  // [384][192] bf16
    const float* __restrict__ bias,
    u16* __restrict__ C,         // [2][Mg][192] bf16
    int Mg)
{
  __shared__ u16 As[128 * 32];
  __shared__ u16 Bs[128 * 32];
  const int t = threadIdx.x;
  const int lane = t & 63, wave = t >> 6;
  const int wm = wave >> 1, wn = wave & 1;
  const int m0 = blockIdx.x * 128;
  const int n0 = blockIdx.y * 128;
  const int lrow = lane >> 2, lcol = lane & 3;
  const int frow = lane & 15, fk = (lane >> 4) * 8;

  f4 acc[4][4];
#pragma unroll
  for (int a = 0; a < 4; a++)
#pragma unroll
    for (int b = 0; b < 4; b++) acc[a][b] = 0.0f;

  for (int ks = 0; ks < 6; ++ks) {
    const int kb = ks * 32;
#pragma unroll
    for (int l = 0; l < 2; ++l) {
      const int r = wave * 32 + l * 16 + lrow;
      gl_lds16(A + (size_t)(m0 + r) * 192 + kb + lcol * 8, As + (wave * 32 + l * 16) * 32);
      gl_lds16(Bw + (size_t)(n0 + r) * 192 + kb + lcol * 8, Bs + (wave * 32 + l * 16) * 32);
    }
    __syncthreads();
    bf8 af[4], bfr[4];
#pragma unroll
    for (int fm = 0; fm < 4; ++fm)
      af[fm] = *(const bf8*)(As + (wm * 64 + fm * 16 + frow) * 32 + fk);
#pragma unroll
    for (int fn = 0; fn < 4; ++fn)
      bfr[fn] = *(const bf8*)(Bs + (wn * 64 + fn * 16 + frow) * 32 + fk);
#pragma unroll
    for (int fm = 0; fm < 4; ++fm)
#pragma unroll
      for (int fn = 0; fn < 4; ++fn)
        acc[fm][fn] = __builtin_amdgcn_mfma_f32_16x16x32_bf16(af[fm], bfr[fn], acc[fm][fn], 0, 0, 0);
    __syncthreads();
  }
  const int r0 = (lane >> 4) * 4, cc = lane & 15;
#pragma unroll
  for (int fn = 0; fn < 4; ++fn) {
    const int col = n0 + wn * 64 + fn * 16 + cc;
    const float bv = bias[col];
    const int hsel = (col >= 192) ? 1 : 0;
    u16* Cp = C + (size_t)hsel * Mg * 192 + (col - hsel * 192);
#pragma unroll
    for (int fm = 0; fm < 4; ++fm) {
      const int mrow = m0 + wm * 64 + fm * 16 + r0;
#pragma unroll
      for (int r = 0; r < 4; ++r)
        Cp[(size_t)(mrow + r) * 192] = f2bf(acc[fm][fn][r] + bv);
    }
  }
}

// ---------------- K4 v3: depthwise 3x3 + GELU, single-barrier LDS tile ----------------
// h1/h2 layout [2][Mg][192]. Block: 192 thr = 24 ch-octets x 8 j. Tile: 8 rows x 8 j x 192ch(half).
// DMA whole 10-row halo tile to LDS (40 wave-issues), ONE barrier, then pure-LDS compute.
__global__ __launch_bounds__(192) void k4_dw(
    const u16* __restrict__ h1,    // [2][Mg][192]
    const float* __restrict__ wdw, // [384*9]
    u16* __restrict__ h2,          // [2][Mg][192]
    int Mg)
{
  const int bx = blockIdx.x;
  const int half = bx & 1;
  const int jt = (bx >> 1) & 15;
  const int rt = (bx >> 5) & 15;
  const int img = bx >> 9;
  const int t = threadIdx.x;
  const int lane = t & 63, wave = t >> 6;
  const int ibase = img * 16384;
  const int r0 = rt * 8;
  const int jBase = (jt == 0) ? 0 : (jt * 8 - 1);
  const int jOff = (jt == 0) ? 0 : 1;
  const size_t hs = (size_t)half * Mg * 192;
  const u16* src = h1 + hs;
  u16* dst = h2 + hs;

  __shared__ u16 lds[10 * 2048];   // [row 0..9][2048 u16 = 10.67 j * 192ch]

  // bulk DMA: 10 rows x 4 segs of 1024 B
  for (int i = wave; i < 40; i += 3) {
    const int r = i >> 2, seg = i & 3;
    const int gr = r0 - 1 + r;
    if (gr >= 0 && gr < 128) {
      const u16* g = src + (size_t)(ibase + gr * 128 + jBase) * 192 + seg * 512 + lane * 8;
      gl_lds16(g, &lds[r * 2048 + seg * 512]);
    }
  }
  if (rt == 0) {
    for (int c = t; c < 256; c += 192) *(u16x8*)&lds[c * 8] = (u16x8)(0);
  }
  if (rt == 15) {
    for (int c = t; c < 256; c += 192) *(u16x8*)&lds[9 * 2048 + c * 8] = (u16x8)(0);
  }
  __syncthreads();   // the ONLY barrier

  const int o = t % 24, jl = t / 24;
  const int jg = jt * 8 + jl;
  const int cl = o * 8;             // channel offset within half
  const int cg = half * 192 + cl;   // global channel

  f2 w2[3][3][4];
#pragma unroll
  for (int dy = 0; dy < 3; dy++)
#pragma unroll
    for (int dx = 0; dx < 3; dx++)
#pragma unroll
      for (int p = 0; p < 4; p++) {
        w2[dy][dx][p][0] = wdw[(cg + 2 * p) * 9 + dy * 3 + dx];
        w2[dy][dx][p][1] = wdw[(cg + 2 * p + 1) * 9 + dy * 3 + dx];
      }

  int im = jl - 1 + jOff; if (im < 0) im = 0;
  const int i0 = jl + jOff, ip = jl + 1 + jOff;

  f2 accA[4], accB[4];
#pragma unroll
  for (int p = 0; p < 4; p++) { accA[p] = (f2)(0.f); accB[p] = (f2)(0.f); }

#pragma unroll
  for (int r = 0; r < 10; ++r) {
    u16x8 vm = *(const u16x8*)&lds[r * 2048 + im * 192 + cl];
    u16x8 v0 = *(const u16x8*)&lds[r * 2048 + i0 * 192 + cl];
    u16x8 vp = *(const u16x8*)&lds[r * 2048 + ip * 192 + cl];
    if (jg == 0)   vm = (u16x8)(0);
    if (jg == 127) vp = (u16x8)(0);
    union { u16x8 v; u32 d[4]; } um, u0, up;
    um.v = vm; u0.v = v0; up.v = vp;
    f2 P0[4], P1[4], P2[4];
#pragma unroll
    for (int p = 0; p < 4; p++) {
      const f2 xm = bfpair(um.d[p]);
      const f2 x0 = bfpair(u0.d[p]);
      const f2 xp = bfpair(up.d[p]);
      P0[p] = w2[0][0][p] * xm + w2[0][1][p] * x0 + w2[0][2][p] * xp;
      P1[p] = w2[1][0][p] * xm + w2[1][1][p] * x0 + w2[1][2][p] * xp;
      P2[p] = w2[2][0][p] * xm + w2[2][1][p] * x0 + w2[2][2][p] * xp;
    }
    if (r >= 2) {
      const int orow = r0 + r - 2;
      u16x8 ov;
#pragma unroll
      for (int p = 0; p < 4; p++) {
        f2 g2 = accA[p] + P2[p];
        ov[2 * p]     = f2bf(gelu_fast(g2[0]));
        ov[2 * p + 1] = f2bf(gelu_fast(g2[1]));
      }
      *(u16x8*)(dst + (size_t)(ibase + orow * 128 + jg) * 192 + cl) = ov;
    }
#pragma unroll
    for (int p = 0; p < 4; p++) {
      accA[p] = accB[p] + P1[p];
      accB[p] = P0[p];
    }
  }
}

// ---------------- K5: GEMM2 + residual + interleave scatter ----------------
__global__ __launch_bounds__(256) void k5_gemm2(
    const u16* __restrict__ A,     // h2 [2][Mg][192]
    const u16* __restrict__ Bw,    // [192][384]
    const u16* __restrict__ high,  // [NPOS][192]
    float* __restrict__ out,       // [8][256][256][64]
    int chunkStart, int Mg)
{
  __shared__ u16 As[128 * 32];
  __shared__ u16 Bs[192 * 32];
  const int t = threadIdx.x;
  const int lane = t & 63, wave = t >> 6;
  const int wm = wave >> 1, wn = wave & 1;
  const int m0 = blockIdx.x * 128;
  const int lrow = lane >> 2, lcol = lane & 3;
  const int frow = lane & 15, fk = (lane >> 4) * 8;

  f4 acc[4][6];
#pragma unroll
  for (int a = 0; a < 4; a++)
#pragma unroll
    for (int b = 0; b < 6; b++) acc[a][b] = 0.0f;

  for (int ks = 0; ks < 12; ++ks) {
    const int kb = ks * 32;
    const u16* Ah = A + (ks >= 6 ? (size_t)Mg * 192 : 0) + (kb - (ks >= 6 ? 192 : 0));
#pragma unroll
    for (int l = 0; l < 2; ++l) {
      const int r = wave * 32 + l * 16 + lrow;
      gl_lds16(Ah + (size_t)(m0 + r) * 192 + lcol * 8, As + (wave * 32 + l * 16) * 32);
    }
#pragma unroll
    for (int l = 0; l < 3; ++l) {
      const int rb = wave * 48 + l * 16 + lrow;
      gl_lds16(Bw + (size_t)rb * 384 + kb + lcol * 8, Bs + (wave * 48 + l * 16) * 32);
    }
    __syncthreads();
    bf8 af[4], bfr[6];
#pragma unroll
    for (int fm = 0; fm < 4; ++fm)
      af[fm] = *(const bf8*)(As + (wm * 64 + fm * 16 + frow) * 32 + fk);
#pragma unroll
    for (int fn = 0; fn < 6; ++fn)
      bfr[fn] = *(const bf8*)(Bs + (wn * 96 + fn * 16 + frow) * 32 + fk);
#pragma unroll
    for (int fm = 0; fm < 4; ++fm)
#pragma unroll
      for (int fn = 0; fn < 6; ++fn)
        acc[fm][fn] = __builtin_amdgcn_mfma_f32_16x16x32_bf16(af[fm], bfr[fn], acc[fm][fn], 0, 0, 0);
    __syncthreads();
  }

  const int r0 = (lane >> 4) * 4, ccol = lane & 15;
#pragma unroll
  for (int fn = 0; fn < 6; ++fn) {
    const int oc = wn * 96 + fn * 16 + ccol;
    const int band = oc >> 6, c = oc & 63;
    const int p = (band + 1) >> 1, q = (band + 1) & 1;
#pragma unroll
    for (int fm = 0; fm < 4; ++fm) {
#pragma unroll
      for (int r = 0; r < 4; ++r) {
        const int m = m0 + wm * 64 + fm * 16 + r0 + r;
        const int np = chunkStart + m;
        const int b = np >> 14, rem = np & 16383, i = rem >> 7, j = rem & 127;
        const float hv = bf2f(high[(size_t)np * 192 + oc]);
        out[((b * 256 + 2 * i + p) * 256 + (2 * j + q)) * 64 + c] = hv + acc[fm][fn][r];
      }
    }
  }
}

extern "C" void kernel_launch(void* const* d_in, const int* in_sizes, int n_in,
                              void* d_out, int out_size, void* d_ws, size_t ws_size,
                              hipStream_t stream)
{
  const float* x        = (const float*)d_in[0];
  const float* gamma    = (const float*)d_in[1];
  const float* beta     = (const float*)d_in[2];
  const float* w_in     = (const float*)d_in[3];
  const float* w_dw     = (const float*)d_in[4];
  const float* w_out    = (const float*)d_in[5];
  const float* res_scale= (const float*)d_in[6];
  float* out = (float*)d_out;
  char* ws = (char*)d_ws;

  float* stats   = (float*)ws;                     // 384 floats
  float* st      = (float*)(ws + 2048);            // 384 floats
  float* bias1   = (float*)(ws + 4096);            // 384 floats
  u16*   w_in_f  = (u16*)(ws + 8192);              // 147456 B
  u16*   w_out_f = (u16*)(ws + 8192 + 147456);     // 147456 B
  u16*   high    = (u16*)(ws + (size_t)(1 << 19)); // 50331648 B
  const size_t off_h1 = (size_t)(1 << 19) + (size_t)NPOS * 192 * 2;
  const size_t imgBytes = (size_t)16384 * 384 * 2; // per image, both halves
  int G = 8;
  while (G > 1 && off_h1 + 2 * (size_t)G * imgBytes > ws_size) G >>= 1;
  u16* h1 = (u16*)(ws + off_h1);
  u16* h2 = (u16*)(ws + off_h1 + (size_t)G * imgBytes);

  k0_zero<<<1, 384, 0, stream>>>(stats);
  k1_dwt<<<1024, 256, 0, stream>>>(x, high, out, stats);
  k2a<<<1, 256, 0, stream>>>(stats, gamma, beta, st);
  k2b<<<576, 64, 0, stream>>>(w_in, w_out, st, res_scale, w_in_f, bias1, w_out_f);

  for (int cs = 0; cs < 8; cs += G) {
    const int chunkStart = cs * 16384;
    const int Mg = G * 16384;
    k3_gemm1<<<dim3(Mg / 128, 3), 256, 0, stream>>>(high + (size_t)chunkStart * 192, w_in_f, bias1, h1, Mg);
    k4_dw<<<G * 512, 192, 0, stream>>>(h1, w_dw, h2, Mg);
    k5_gemm2<<<dim3(Mg / 128, 1), 256, 0, stream>>>(h2, w_out_f, high, out, chunkStart, Mg);
  }
}